// Round 18
// baseline (100.160 us; speedup 1.0000x reference)
//
#include <hip/hip_runtime.h>
#include <hip/hip_bf16.h>
#include <math.h>

#define NH 8
#define D 64
#define BB 2
#define SS 2048
#define NBH (BB*NH)
#define LOG2E 1.4426950408889634f
#define KPAR 8   // k-parity classes in colstats
#define QPAR 4   // q-parity classes in pv

typedef short bf16x8 __attribute__((ext_vector_type(8)));
typedef float f32x4 __attribute__((ext_vector_type(4)));

#define MFMA16(a,b,c) __builtin_amdgcn_mfma_f32_16x16x32_bf16((a),(b),(c),0,0,0)

// bijective XCD-aware block swizzle (nwg % 8 == 0)
__device__ inline int xcd_swz(int orig, int nwg) {
    int cpx = nwg >> 3;
    return (orig & 7) * cpx + (orig >> 3);
}

// round-to-nearest-even f32 -> bf16
__device__ inline short f2bf(float f) {
    unsigned u = __float_as_uint(f);
    unsigned r = (u + 0x7fffu + ((u >> 16) & 1u)) >> 16;
    return (short)r;
}
__device__ inline float bf2f(short s) {
    return __uint_as_float(((unsigned)(unsigned short)s) << 16);
}
// pack two f32 -> u32 of 2 bf16 (RNE), low = a
__device__ inline unsigned pack2bf(float a, float b) {
    __hip_bfloat162 hv = __float22bfloat162_rn(make_float2(a, b));
    unsigned u;
    __builtin_memcpy(&u, &hv, 4);
    return u;
}

// ---------- Kernel 0: W transposes -> bf16 ------------------------------------
// blocks 0..23: Wq/Wk/Wv [h][z][d] -> WT[h][d][z]
// blocks 24..39: Wo[z][d] (512x64) -> WoT[d][z'] (64x2048), z' = z duplicated 4x
__global__ __launch_bounds__(256) void wtrans_kernel(
    const float* __restrict__ Wq, const float* __restrict__ Wk,
    const float* __restrict__ Wv, const float* __restrict__ Wo,
    short* __restrict__ WqT, short* __restrict__ WkT, short* __restrict__ WvT,
    short* __restrict__ WoT) {
    int blk = blockIdx.x;
    int t = threadIdx.x;
    if (blk < 24) {
        int tensor = blk >> 3, h = blk & 7;
        const float* W = tensor == 0 ? Wq : (tensor == 1 ? Wk : Wv);
        short* WT = tensor == 0 ? WqT : (tensor == 1 ? WkT : WvT);
        __shared__ float wl[64][65];
        {
            int z = t >> 2, c0 = (t & 3) * 16;
            const float* src = W + (size_t)h * 4096 + (size_t)z * 64 + c0;
#pragma unroll
            for (int i = 0; i < 16; ++i) wl[z][c0 + i] = src[i];
        }
        __syncthreads();
        {
            int d = t >> 2, z0 = (t & 3) * 16;
            short* dst = WT + ((size_t)h * 64 + d) * 64 + z0;
#pragma unroll
            for (int i = 0; i < 16; ++i) dst[i] = f2bf(wl[z0 + i][d]);
        }
    } else {
        int idx = (blk - 24) * 256 + t;   // 0..4095
        int d = idx >> 6;                 // 0..63
        int zc = (idx & 63) * 32;         // 0..2016
#pragma unroll
        for (int j = 0; j < 32; ++j) {
            int z = zc + j;
            WoT[(size_t)d * 2048 + z] = f2bf(Wo[(size_t)(z & 511) * 64 + d]);
        }
    }
}

// ---------- Kernel 1: fused QKV projection via MFMA ---------------------------
// tensor 0: rope + LOG2E/64 scale -> qh; 1: rope -> kh; 2: transpose -> vhT
__global__ __launch_bounds__(256) void proj_mfma_kernel(
    const float* __restrict__ xq, const float* __restrict__ xk,
    const float* __restrict__ xv,
    const short* __restrict__ WqT, const short* __restrict__ WkT,
    const short* __restrict__ WvT,
    short* __restrict__ qh, short* __restrict__ kh, short* __restrict__ vhT) {
    int blk = xcd_swz(blockIdx.x, 3 * NBH * 32);
    int tensor = blk / (NBH * 32);
    int rem = blk - tensor * (NBH * 32);
    int st = rem & 31, bh = rem >> 5;
    int h = bh & 7, b = bh >> 3;
    const float* x = tensor == 0 ? xq : (tensor == 1 ? xk : xv);
    const short* WT = tensor == 0 ? WqT : (tensor == 1 ? WkT : WvT);

    int t = threadIdx.x, w = t >> 6, lane = t & 63;
    int l15 = lane & 15, lg = lane >> 4;

    __shared__ short vt[64 * 64];

    int sA = st * 64 + w * 16 + l15;
    const float* xr = x + ((size_t)b * SS + sA) * D + lg * 8;
    bf16x8 a0, a1;
#pragma unroll
    for (int j = 0; j < 8; ++j) a0[j] = f2bf(xr[j]);
#pragma unroll
    for (int j = 0; j < 8; ++j) a1[j] = f2bf(xr[32 + j]);

    bf16x8 bfr[4][2];
#pragma unroll
    for (int ds_ = 0; ds_ < 4; ++ds_) {
        int d = ds_ * 16 + l15;
        const short* wp = WT + ((size_t)h * 64 + d) * 64 + lg * 8;
        bfr[ds_][0] = *(const bf16x8*)(wp);
        bfr[ds_][1] = *(const bf16x8*)(wp + 32);
    }

    f32x4 c[4];
#pragma unroll
    for (int ds_ = 0; ds_ < 4; ++ds_) {
        f32x4 z = {0.f, 0.f, 0.f, 0.f};
        z = MFMA16(a0, bfr[ds_][0], z);
        z = MFMA16(a1, bfr[ds_][1], z);
        c[ds_] = z;
    }

    int sbase = st * 64 + w * 16 + lg * 4;
    if (tensor < 2) {
        short* dst = tensor == 0 ? qh : kh;
        float scale = tensor == 0 ? (LOG2E / 64.0f) : 1.0f;
#pragma unroll
        for (int ds_ = 0; ds_ < 4; ++ds_) {
            int d = ds_ * 16 + l15;
            float invf = exp2f(-(float)(d & ~1) * (13.287712379549449f / 64.0f));
#pragma unroll
            for (int r = 0; r < 4; ++r) {
                float v = c[ds_][r];
                float pr = __shfl_xor(v, 1);
                float ang = (float)(sbase + r) * invf;
                float cs = __cosf(ang), sn = __sinf(ang);
                float o = (d & 1) ? (pr * sn + v * cs) : (v * cs - pr * sn);
                dst[((size_t)bh * SS + sbase + r) * D + d] = f2bf(o * scale);
            }
        }
    } else {
#pragma unroll
        for (int ds_ = 0; ds_ < 4; ++ds_) {
            int d = ds_ * 16 + l15;
#pragma unroll
            for (int r = 0; r < 4; ++r) {
                int sc = w * 16 + lg * 4 + r;
                vt[d * 64 + (sc ^ ((d & 7) << 3))] = f2bf(c[ds_][r]);
            }
        }
        __syncthreads();
#pragma unroll
        for (int pp = 0; pp < 2; ++pp) {
            int idx = pp * 256 + t;
            int d = idx >> 3, a = idx & 7;
            bf16x8 val = *(const bf16x8*)&vt[d * 64 + ((a ^ (d & 7)) << 3)];
            *(bf16x8*)&vhT[((size_t)bh * D + d) * SS + st * 64 + a * 8] = val;
        }
    }
}

// ---------- Kernel 2: per-q softmax denominators (Q pre-scaled: exp2(s)) ------
// grid = NBH*64: blk -> (bh, qp in 0..15, ph in 0..3). Wave w:
// qt = ((w&1)^(qp>>3)) ? 31-qp : qp  (SIMD-balanced vs co-residency pattern),
// pp = ph*2 + (w>>1) -> 8 k-parity classes.
__global__ __launch_bounds__(256, 4) void colstats_kernel(
    const short* __restrict__ qh, const short* __restrict__ kh,
    float* __restrict__ lpart) {
    int blk = xcd_swz(blockIdx.x, NBH * 64);
    int ph = blk & 3, qp = (blk >> 2) & 15, bh = blk >> 6;
    int t = threadIdx.x, w = t >> 6, lane = t & 63;
    int l15 = lane & 15, lg = lane >> 4;
    int qsel = (w ^ (qp >> 3)) & 1;
    int qt = qsel ? (31 - qp) : qp;
    int pp = ph * 2 + (w >> 1);

    bf16x8 qb[4][2];
#pragma unroll
    for (int qs = 0; qs < 4; ++qs) {
        const short* qp2 = qh + ((size_t)bh * SS + qt * 64 + qs * 16 + l15) * D + lg * 8;
        qb[qs][0] = *(const bf16x8*)qp2;
        qb[qs][1] = *(const bf16x8*)(qp2 + 32);
    }

    const short* kbase = kh + (size_t)bh * SS * D;
    float lsum[4] = {0.f, 0.f, 0.f, 0.f};

    for (int kt = pp; kt <= qt; kt += KPAR) {
        bool diag = (kt == qt);
#pragma unroll
        for (int ks = 0; ks < 4; ++ks) {
            const short* kp = kbase + (size_t)(kt * 64 + ks * 16 + l15) * D + lg * 8;
            bf16x8 ka0 = *(const bf16x8*)kp;
            bf16x8 ka1 = *(const bf16x8*)(kp + 32);
            int kb = kt * 64 + ks * 16 + lg * 4;
#pragma unroll
            for (int qs = 0; qs < 4; ++qs) {
                f32x4 s = {0.f, 0.f, 0.f, 0.f};
                s = MFMA16(ka0, qb[qs][0], s);
                s = MFMA16(ka1, qb[qs][1], s);
                int qc = qt * 64 + qs * 16 + l15;
#pragma unroll
                for (int r = 0; r < 4; ++r) {
                    float e = (!diag || kb + r <= qc) ? exp2f(s[r]) : 0.f;
                    lsum[qs] += e;
                }
            }
        }
    }
#pragma unroll
    for (int qs = 0; qs < 4; ++qs) {
        lsum[qs] += __shfl_xor(lsum[qs], 16);
        lsum[qs] += __shfl_xor(lsum[qs], 32);
    }
    if (lane < 16) {
#pragma unroll
        for (int qs = 0; qs < 4; ++qs)
            lpart[((size_t)pp * NBH + bh) * SS + qt * 64 + qs * 16 + lane] = lsum[qs];
    }
}

// ---------- Kernel 2b: merge partials + fold 1/l into V (fused) ---------------
// grid = NBH*16 (bh, 128-q chunk), 256 thr.
__global__ __launch_bounds__(256) void merge_scale_kernel(
    const float* __restrict__ lpart, short* __restrict__ vhT) {
    int blk = blockIdx.x;
    int qc = blk & 15, bh = blk >> 4;
    int t = threadIdx.x;
    const size_t STR = (size_t)NBH * SS;
    __shared__ float il[128];
    if (t < 128) {
        size_t idx = (size_t)bh * SS + qc * 128 + t;
        float l = 0.f;
#pragma unroll
        for (int pp = 0; pp < KPAR; ++pp) l += lpart[pp * STR + idx];
        il[t] = 1.0f / l;
    }
    __syncthreads();
    int d = t >> 2, sub = t & 3;
    size_t base = ((size_t)bh * 64 + d) * SS + qc * 128 + sub * 32;
#pragma unroll
    for (int j = 0; j < 32; j += 8) {
        bf16x8 v = *(bf16x8*)&vhT[base + j];
#pragma unroll
        for (int jj = 0; jj < 8; ++jj)
            v[jj] = f2bf(bf2f(v[jj]) * il[sub * 32 + j + jj]);
        *(bf16x8*)&vhT[base + j] = v;
    }
}

// ---------- Kernel 3: PV (swapped QK, packed P-writes, 2-qt ILP interleave) ---
// grid = NBH*64: blk -> (bh, pair p, q-parity ph). Wave w:
// kt = ((w&1)^(p>>3)) ? 31-p : p  (SIMD-balanced vs co-residency pattern),
// hf = w>>1 -> 32 k-rows. Two q-tiles per iteration with independent LDS
// P-buffers. V pre-scaled by 1/l_q; Q pre-scaled LOG2E/64.
// attc[b][k][ph*512 + h*64 + d] bf16.
__global__ __launch_bounds__(256, 4) void pv_kernel(
    const short* __restrict__ qh, const short* __restrict__ kh,
    const short* __restrict__ vhT,
    short* __restrict__ attc) {
    int blk = xcd_swz(blockIdx.x, NBH * 64);
    int ph = blk & 3, p = (blk >> 2) & 15, bh = blk >> 6;
    int h = bh & 7, b = bh >> 3;
    int t = threadIdx.x, w = t >> 6, lane = t & 63;
    int l15 = lane & 15, lg = lane >> 4;
    int sel = (w ^ (p >> 3)) & 1;
    int kt = sel ? (31 - p) : p;
    int hf = w >> 1;
    int row0 = kt * 64 + hf * 32;

    __shared__ short pl[4][2][32 * 64];   // 32 KB: 2 P-buffers per wave

    // K B-frags for the wave's 32 k-rows (kg = 0,1)
    bf16x8 kb[2][2];
#pragma unroll
    for (int kg = 0; kg < 2; ++kg) {
        const short* kp = kh + ((size_t)bh * SS + row0 + kg * 16 + l15) * D + lg * 8;
        kb[kg][0] = *(const bf16x8*)kp;
        kb[kg][1] = *(const bf16x8*)(kp + 32);
    }

    f32x4 acc[2][4];
#pragma unroll
    for (int rg = 0; rg < 2; ++rg)
#pragma unroll
        for (int i = 0; i < 4; ++i) acc[rg][i] = (f32x4){0.f, 0.f, 0.f, 0.f};

    const short* qbase = qh + (size_t)bh * SS * D;
    const short* vbase = vhT + (size_t)bh * D * SS;

    // QK^T + exp + packed P-write into the given buffer (wave-private, in-order)
    auto qk_store = [&](int qt, short* plw) {
        bool diag = (qt == kt);
        bf16x8 qa[4][2];
#pragma unroll
        for (int qg = 0; qg < 4; ++qg) {
            const short* qp2 = qbase + (size_t)(qt * 64 + qg * 16 + l15) * D + lg * 8;
            qa[qg][0] = *(const bf16x8*)qp2;
            qa[qg][1] = *(const bf16x8*)(qp2 + 32);
        }
#pragma unroll
        for (int qg = 0; qg < 4; ++qg) {
#pragma unroll
            for (int kg = 0; kg < 2; ++kg) {
                f32x4 s = {0.f, 0.f, 0.f, 0.f};
                s = MFMA16(qa[qg][0], kb[kg][0], s);
                s = MFMA16(qa[qg][1], kb[kg][1], s);
                float p0 = exp2f(s[0]);
                float p1 = exp2f(s[1]);
                float p2 = exp2f(s[2]);
                float p3 = exp2f(s[3]);
                if (diag) {
                    int qoff = qg * 16 + 4 * lg;
                    int kk = hf * 32 + kg * 16 + l15;
                    if (qoff + 0 <= kk) p0 = 0.f;
                    if (qoff + 1 <= kk) p1 = 0.f;
                    if (qoff + 2 <= kk) p2 = 0.f;
                    if (qoff + 3 <= kk) p3 = 0.f;
                }
                unsigned u0 = pack2bf(p0, p1);
                unsigned u1 = pack2bf(p2, p3);
                int row = kg * 16 + l15;
                int col = (qg * 16 + 4 * lg) ^ ((row & 7) << 3);
                uint2 val;
                val.x = u0;
                val.y = u1;
                *(uint2*)&plw[row * 64 + col] = val;
            }
        }
    };
    // PV accumulate from the given buffer
    auto pv_acc = [&](int qt, const short* plw) {
#pragma unroll
        for (int qhh = 0; qhh < 2; ++qhh) {
            int chunk = (qhh << 2) | lg;
            int cc = (chunk ^ (l15 & 7)) << 3;
            bf16x8 pa0 = *(const bf16x8*)&plw[l15 * 64 + cc];
            bf16x8 pa1 = *(const bf16x8*)&plw[(16 + l15) * 64 + cc];
#pragma unroll
            for (int ds_ = 0; ds_ < 4; ++ds_) {
                const short* vp2 = vbase + (size_t)(ds_ * 16 + l15) * SS + qt * 64 + chunk * 8;
                bf16x8 vb = *(const bf16x8*)vp2;
                acc[0][ds_] = MFMA16(pa0, vb, acc[0][ds_]);
                acc[1][ds_] = MFMA16(pa1, vb, acc[1][ds_]);
            }
        }
    };

    int qt0 = kt + ((ph - kt) & (QPAR - 1));
    int qt = qt0;
    for (; qt + QPAR < 32; qt += 2 * QPAR) {
        // two independent QK chains -> compiler overlaps loads/MFMA/exp
        qk_store(qt, pl[w][0]);
        qk_store(qt + QPAR, pl[w][1]);
        __builtin_amdgcn_s_setprio(1);
        pv_acc(qt, pl[w][0]);
        pv_acc(qt + QPAR, pl[w][1]);
        __builtin_amdgcn_s_setprio(0);
    }
    if (qt < 32) {
        qk_store(qt, pl[w][0]);
        __builtin_amdgcn_s_setprio(1);
        pv_acc(qt, pl[w][0]);
        __builtin_amdgcn_s_setprio(0);
    }

#pragma unroll
    for (int rg = 0; rg < 2; ++rg)
#pragma unroll
        for (int ds_ = 0; ds_ < 4; ++ds_) {
            int d = ds_ * 16 + l15;
#pragma unroll
            for (int r = 0; r < 4; ++r) {
                int k = row0 + rg * 16 + lg * 4 + r;
                attc[((size_t)b * SS + k) * 2048 + ph * 512 + h * 64 + d] =
                    f2bf(acc[rg][ds_][r]);
            }
        }
}

// ---------- Kernel 4: out = attc(4096x2048) @ [Wo x4](2048x64) via MFMA -------
__global__ __launch_bounds__(256) void outproj_kernel(
    const short* __restrict__ attc, const short* __restrict__ WoT,
    float* __restrict__ out) {
    int blk = blockIdx.x;
    int t = threadIdx.x, w = t >> 6, lane = t & 63;
    int l15 = lane & 15, lg = lane >> 4;
    int srow = blk * 16 + l15;
    const short* arow = attc + (size_t)srow * 2048 + lg * 8;

    f32x4 acc[4];
#pragma unroll
    for (int i = 0; i < 4; ++i) acc[i] = (f32x4){0.f, 0.f, 0.f, 0.f};

#pragma unroll
    for (int i = 0; i < 16; ++i) {
        int kc = w * 16 + i;
        bf16x8 af = *(const bf16x8*)(arow + kc * 32);
#pragma unroll
        for (int ds_ = 0; ds_ < 4; ++ds_) {
            bf16x8 bf_ = *(const bf16x8*)&WoT[(size_t)(ds_ * 16 + l15) * 2048 + kc * 32 + lg * 8];
            acc[ds_] = MFMA16(af, bf_, acc[ds_]);
        }
    }
    __shared__ float red[4][16 * 64];
#pragma unroll
    for (int ds_ = 0; ds_ < 4; ++ds_)
#pragma unroll
        for (int r = 0; r < 4; ++r)
            red[w][(lg * 4 + r) * 64 + ds_ * 16 + l15] = acc[ds_][r];
    __syncthreads();
    {
        int idx4 = t * 4;
        int row = idx4 >> 6, col = idx4 & 63;
        float4 s0 = *(const float4*)&red[0][row * 64 + col];
        float4 s1 = *(const float4*)&red[1][row * 64 + col];
        float4 s2 = *(const float4*)&red[2][row * 64 + col];
        float4 s3 = *(const float4*)&red[3][row * 64 + col];
        float4 sum;
        sum.x = s0.x + s1.x + s2.x + s3.x;
        sum.y = s0.y + s1.y + s2.y + s3.y;
        sum.z = s0.z + s1.z + s2.z + s3.z;
        sum.w = s0.w + s1.w + s2.w + s3.w;
        *(float4*)&out[(size_t)(blk * 16 + row) * 64 + col] = sum;
    }
}

extern "C" void kernel_launch(void* const* d_in, const int* in_sizes, int n_in,
                              void* d_out, int out_size, void* d_ws, size_t ws_size,
                              hipStream_t stream) {
    const float* q  = (const float*)d_in[0];
    const float* k  = (const float*)d_in[1];
    const float* v  = (const float*)d_in[2];
    const float* Wq = (const float*)d_in[3];
    const float* Wk = (const float*)d_in[4];
    const float* Wv = (const float*)d_in[5];
    const float* Wo = (const float*)d_in[6];
    float* out = (float*)d_out;

    const size_t PROJ = (size_t)NBH * SS * D;

    short* qh  = (short*)d_ws;
    short* kh  = qh + PROJ;
    short* vhT = kh + PROJ;
    short* WqT = vhT + PROJ;
    short* WkT = WqT + 32768;
    short* WvT = WkT + 32768;
    short* WoT = WvT + 32768;                         // 64*2048
    float* lpart = (float*)(WoT + 131072);            // KPAR*NBH*SS floats
    short* attc  = (short*)(lpart + (size_t)KPAR * NBH * SS);  // BB*SS*2048 bf16

    wtrans_kernel<<<40, 256, 0, stream>>>(Wq, Wk, Wv, Wo, WqT, WkT, WvT, WoT);

    proj_mfma_kernel<<<3 * NBH * 32, 256, 0, stream>>>(q, k, v, WqT, WkT, WvT,
                                                       qh, kh, vhT);

    colstats_kernel<<<NBH * 64, 256, 0, stream>>>(qh, kh, lpart);

    merge_scale_kernel<<<NBH * 16, 256, 0, stream>>>(lpart, vhT);

    pv_kernel<<<NBH * 64, 256, 0, stream>>>(qh, kh, vhT, attc);

    outproj_kernel<<<256, 256, 0, stream>>>(attc, WoT, out);
}

// Round 19
// 99.204 us; speedup vs baseline: 1.0096x; 1.0096x over previous
//
#include <hip/hip_runtime.h>
#include <hip/hip_bf16.h>
#include <math.h>

#define NH 8
#define D 64
#define BB 2
#define SS 2048
#define NBH (BB*NH)
#define LOG2E 1.4426950408889634f
#define KPAR 8   // k-parity classes in colstats
#define QPAR 4   // q-parity classes in pv

typedef short bf16x8 __attribute__((ext_vector_type(8)));
typedef float f32x4 __attribute__((ext_vector_type(4)));

#define MFMA16(a,b,c) __builtin_amdgcn_mfma_f32_16x16x32_bf16((a),(b),(c),0,0,0)

// bijective XCD-aware block swizzle (nwg % 8 == 0)
__device__ inline int xcd_swz(int orig, int nwg) {
    int cpx = nwg >> 3;
    return (orig & 7) * cpx + (orig >> 3);
}

// round-to-nearest-even f32 -> bf16
__device__ inline short f2bf(float f) {
    unsigned u = __float_as_uint(f);
    unsigned r = (u + 0x7fffu + ((u >> 16) & 1u)) >> 16;
    return (short)r;
}
__device__ inline float bf2f(short s) {
    return __uint_as_float(((unsigned)(unsigned short)s) << 16);
}
// pack two f32 -> u32 of 2 bf16 (RNE), low = a
__device__ inline unsigned pack2bf(float a, float b) {
    __hip_bfloat162 hv = __float22bfloat162_rn(make_float2(a, b));
    unsigned u;
    __builtin_memcpy(&u, &hv, 4);
    return u;
}

// ---------- Kernel 0: W transposes -> bf16 ------------------------------------
// blocks 0..23: Wq/Wk/Wv [h][z][d] -> WT[h][d][z]
// blocks 24..39: Wo[z][d] (512x64) -> WoT[d][z'] (64x2048), z' = z duplicated 4x
__global__ __launch_bounds__(256) void wtrans_kernel(
    const float* __restrict__ Wq, const float* __restrict__ Wk,
    const float* __restrict__ Wv, const float* __restrict__ Wo,
    short* __restrict__ WqT, short* __restrict__ WkT, short* __restrict__ WvT,
    short* __restrict__ WoT) {
    int blk = blockIdx.x;
    int t = threadIdx.x;
    if (blk < 24) {
        int tensor = blk >> 3, h = blk & 7;
        const float* W = tensor == 0 ? Wq : (tensor == 1 ? Wk : Wv);
        short* WT = tensor == 0 ? WqT : (tensor == 1 ? WkT : WvT);
        __shared__ float wl[64][65];
        {
            int z = t >> 2, c0 = (t & 3) * 16;
            const float* src = W + (size_t)h * 4096 + (size_t)z * 64 + c0;
#pragma unroll
            for (int i = 0; i < 16; ++i) wl[z][c0 + i] = src[i];
        }
        __syncthreads();
        {
            int d = t >> 2, z0 = (t & 3) * 16;
            short* dst = WT + ((size_t)h * 64 + d) * 64 + z0;
#pragma unroll
            for (int i = 0; i < 16; ++i) dst[i] = f2bf(wl[z0 + i][d]);
        }
    } else {
        int idx = (blk - 24) * 256 + t;   // 0..4095
        int d = idx >> 6;                 // 0..63
        int zc = (idx & 63) * 32;         // 0..2016
#pragma unroll
        for (int j = 0; j < 32; ++j) {
            int z = zc + j;
            WoT[(size_t)d * 2048 + z] = f2bf(Wo[(size_t)(z & 511) * 64 + d]);
        }
    }
}

// ---------- Kernel 1: fused QKV projection via MFMA ---------------------------
// tensor 0: rope + LOG2E/64 scale -> qh; 1: rope -> kh; 2: transpose -> vhT
__global__ __launch_bounds__(256) void proj_mfma_kernel(
    const float* __restrict__ xq, const float* __restrict__ xk,
    const float* __restrict__ xv,
    const short* __restrict__ WqT, const short* __restrict__ WkT,
    const short* __restrict__ WvT,
    short* __restrict__ qh, short* __restrict__ kh, short* __restrict__ vhT) {
    int blk = xcd_swz(blockIdx.x, 3 * NBH * 32);
    int tensor = blk / (NBH * 32);
    int rem = blk - tensor * (NBH * 32);
    int st = rem & 31, bh = rem >> 5;
    int h = bh & 7, b = bh >> 3;
    const float* x = tensor == 0 ? xq : (tensor == 1 ? xk : xv);
    const short* WT = tensor == 0 ? WqT : (tensor == 1 ? WkT : WvT);

    int t = threadIdx.x, w = t >> 6, lane = t & 63;
    int l15 = lane & 15, lg = lane >> 4;

    __shared__ short vt[64 * 64];

    int sA = st * 64 + w * 16 + l15;
    const float* xr = x + ((size_t)b * SS + sA) * D + lg * 8;
    bf16x8 a0, a1;
#pragma unroll
    for (int j = 0; j < 8; ++j) a0[j] = f2bf(xr[j]);
#pragma unroll
    for (int j = 0; j < 8; ++j) a1[j] = f2bf(xr[32 + j]);

    bf16x8 bfr[4][2];
#pragma unroll
    for (int ds_ = 0; ds_ < 4; ++ds_) {
        int d = ds_ * 16 + l15;
        const short* wp = WT + ((size_t)h * 64 + d) * 64 + lg * 8;
        bfr[ds_][0] = *(const bf16x8*)(wp);
        bfr[ds_][1] = *(const bf16x8*)(wp + 32);
    }

    f32x4 c[4];
#pragma unroll
    for (int ds_ = 0; ds_ < 4; ++ds_) {
        f32x4 z = {0.f, 0.f, 0.f, 0.f};
        z = MFMA16(a0, bfr[ds_][0], z);
        z = MFMA16(a1, bfr[ds_][1], z);
        c[ds_] = z;
    }

    int sbase = st * 64 + w * 16 + lg * 4;
    if (tensor < 2) {
        short* dst = tensor == 0 ? qh : kh;
        float scale = tensor == 0 ? (LOG2E / 64.0f) : 1.0f;
#pragma unroll
        for (int ds_ = 0; ds_ < 4; ++ds_) {
            int d = ds_ * 16 + l15;
            float invf = exp2f(-(float)(d & ~1) * (13.287712379549449f / 64.0f));
#pragma unroll
            for (int r = 0; r < 4; ++r) {
                float v = c[ds_][r];
                float pr = __shfl_xor(v, 1);
                float ang = (float)(sbase + r) * invf;
                float cs = __cosf(ang), sn = __sinf(ang);
                float o = (d & 1) ? (pr * sn + v * cs) : (v * cs - pr * sn);
                dst[((size_t)bh * SS + sbase + r) * D + d] = f2bf(o * scale);
            }
        }
    } else {
#pragma unroll
        for (int ds_ = 0; ds_ < 4; ++ds_) {
            int d = ds_ * 16 + l15;
#pragma unroll
            for (int r = 0; r < 4; ++r) {
                int sc = w * 16 + lg * 4 + r;
                vt[d * 64 + (sc ^ ((d & 7) << 3))] = f2bf(c[ds_][r]);
            }
        }
        __syncthreads();
#pragma unroll
        for (int pp = 0; pp < 2; ++pp) {
            int idx = pp * 256 + t;
            int d = idx >> 3, a = idx & 7;
            bf16x8 val = *(const bf16x8*)&vt[d * 64 + ((a ^ (d & 7)) << 3)];
            *(bf16x8*)&vhT[((size_t)bh * D + d) * SS + st * 64 + a * 8] = val;
        }
    }
}

// ---------- Kernel 2: per-q softmax denominators (Q pre-scaled: exp2(s)) ------
// grid = NBH*64: blk -> (bh, qp in 0..15, ph in 0..3). Wave w:
// qt = ((w&1)^(qp>>3)) ? 31-qp : qp  (SIMD-balanced vs co-residency pattern),
// pp = ph*2 + (w>>1) -> 8 k-parity classes. K loads hoisted in ks-PAIRS so the
// vmcnt waits amortize (4 loads in flight instead of load->wait->use x4).
__global__ __launch_bounds__(256, 4) void colstats_kernel(
    const short* __restrict__ qh, const short* __restrict__ kh,
    float* __restrict__ lpart) {
    int blk = xcd_swz(blockIdx.x, NBH * 64);
    int ph = blk & 3, qp = (blk >> 2) & 15, bh = blk >> 6;
    int t = threadIdx.x, w = t >> 6, lane = t & 63;
    int l15 = lane & 15, lg = lane >> 4;
    int qsel = (w ^ (qp >> 3)) & 1;
    int qt = qsel ? (31 - qp) : qp;
    int pp = ph * 2 + (w >> 1);

    bf16x8 qb[4][2];
#pragma unroll
    for (int qs = 0; qs < 4; ++qs) {
        const short* qp2 = qh + ((size_t)bh * SS + qt * 64 + qs * 16 + l15) * D + lg * 8;
        qb[qs][0] = *(const bf16x8*)qp2;
        qb[qs][1] = *(const bf16x8*)(qp2 + 32);
    }

    const short* kbase = kh + (size_t)bh * SS * D;
    float lsum[4] = {0.f, 0.f, 0.f, 0.f};

    for (int kt = pp; kt <= qt; kt += KPAR) {
        bool diag = (kt == qt);
#pragma unroll
        for (int ksp = 0; ksp < 2; ++ksp) {
            // batched K loads for two ks sub-tiles (4 loads in flight)
            bf16x8 ka[2][2];
#pragma unroll
            for (int kss = 0; kss < 2; ++kss) {
                int ks = ksp * 2 + kss;
                const short* kp = kbase + (size_t)(kt * 64 + ks * 16 + l15) * D + lg * 8;
                ka[kss][0] = *(const bf16x8*)kp;
                ka[kss][1] = *(const bf16x8*)(kp + 32);
            }
#pragma unroll
            for (int kss = 0; kss < 2; ++kss) {
                int ks = ksp * 2 + kss;
                int kb = kt * 64 + ks * 16 + lg * 4;
#pragma unroll
                for (int qs = 0; qs < 4; ++qs) {
                    f32x4 s = {0.f, 0.f, 0.f, 0.f};
                    s = MFMA16(ka[kss][0], qb[qs][0], s);
                    s = MFMA16(ka[kss][1], qb[qs][1], s);
                    int qc = qt * 64 + qs * 16 + l15;
#pragma unroll
                    for (int r = 0; r < 4; ++r) {
                        float e = (!diag || kb + r <= qc) ? exp2f(s[r]) : 0.f;
                        lsum[qs] += e;
                    }
                }
            }
        }
    }
#pragma unroll
    for (int qs = 0; qs < 4; ++qs) {
        lsum[qs] += __shfl_xor(lsum[qs], 16);
        lsum[qs] += __shfl_xor(lsum[qs], 32);
    }
    if (lane < 16) {
#pragma unroll
        for (int qs = 0; qs < 4; ++qs)
            lpart[((size_t)pp * NBH + bh) * SS + qt * 64 + qs * 16 + lane] = lsum[qs];
    }
}

// ---------- Kernel 2b: merge partials + fold 1/l into V (fused) ---------------
// grid = NBH*16 (bh, 128-q chunk), 256 thr.
__global__ __launch_bounds__(256) void merge_scale_kernel(
    const float* __restrict__ lpart, short* __restrict__ vhT) {
    int blk = blockIdx.x;
    int qc = blk & 15, bh = blk >> 4;
    int t = threadIdx.x;
    const size_t STR = (size_t)NBH * SS;
    __shared__ float il[128];
    if (t < 128) {
        size_t idx = (size_t)bh * SS + qc * 128 + t;
        float l = 0.f;
#pragma unroll
        for (int pp = 0; pp < KPAR; ++pp) l += lpart[pp * STR + idx];
        il[t] = 1.0f / l;
    }
    __syncthreads();
    int d = t >> 2, sub = t & 3;
    size_t base = ((size_t)bh * 64 + d) * SS + qc * 128 + sub * 32;
#pragma unroll
    for (int j = 0; j < 32; j += 8) {
        bf16x8 v = *(bf16x8*)&vhT[base + j];
#pragma unroll
        for (int jj = 0; jj < 8; ++jj)
            v[jj] = f2bf(bf2f(v[jj]) * il[sub * 32 + j + jj]);
        *(bf16x8*)&vhT[base + j] = v;
    }
}

// ---------- Kernel 3: PV (swapped QK, packed P-writes, BATCHED V loads) -------
// grid = NBH*64: blk -> (bh, pair p, q-parity ph). Wave w:
// kt = ((w&1)^(p>>3)) ? 31-p : p, hf = w>>1 -> 32 k-rows.
// Per qt-step: QK phase (qa transient) -> ALL 8 V-frag loads issued together
// (fly concurrently, overlapping the P LDS round-trip) -> 16 PV MFMAs.
// V pre-scaled by 1/l_q; Q pre-scaled LOG2E/64.
// attc[b][k][ph*512 + h*64 + d] bf16.
__global__ __launch_bounds__(256, 4) void pv_kernel(
    const short* __restrict__ qh, const short* __restrict__ kh,
    const short* __restrict__ vhT,
    short* __restrict__ attc) {
    int blk = xcd_swz(blockIdx.x, NBH * 64);
    int ph = blk & 3, p = (blk >> 2) & 15, bh = blk >> 6;
    int h = bh & 7, b = bh >> 3;
    int t = threadIdx.x, w = t >> 6, lane = t & 63;
    int l15 = lane & 15, lg = lane >> 4;
    int sel = (w ^ (p >> 3)) & 1;
    int kt = sel ? (31 - p) : p;
    int hf = w >> 1;
    int row0 = kt * 64 + hf * 32;

    __shared__ short pl[4][32 * 64];
    short* plw = pl[w];

    // K B-frags for the wave's 32 k-rows (kg = 0,1)
    bf16x8 kb[2][2];
#pragma unroll
    for (int kg = 0; kg < 2; ++kg) {
        const short* kp = kh + ((size_t)bh * SS + row0 + kg * 16 + l15) * D + lg * 8;
        kb[kg][0] = *(const bf16x8*)kp;
        kb[kg][1] = *(const bf16x8*)(kp + 32);
    }

    f32x4 acc[2][4];
#pragma unroll
    for (int rg = 0; rg < 2; ++rg)
#pragma unroll
        for (int i = 0; i < 4; ++i) acc[rg][i] = (f32x4){0.f, 0.f, 0.f, 0.f};

    const short* qbase = qh + (size_t)bh * SS * D;
    const short* vbase = vhT + (size_t)bh * D * SS;

    int qt0 = kt + ((ph - kt) & (QPAR - 1));
    for (int qt = qt0; qt < 32; qt += QPAR) {
        bool diag = (qt == kt);
        // ---- QK phase: qa transient (dies before V loads) ----
        {
            bf16x8 qa[4][2];
#pragma unroll
            for (int qg = 0; qg < 4; ++qg) {
                const short* qp2 = qbase + (size_t)(qt * 64 + qg * 16 + l15) * D + lg * 8;
                qa[qg][0] = *(const bf16x8*)qp2;
                qa[qg][1] = *(const bf16x8*)(qp2 + 32);
            }
#pragma unroll
            for (int qg = 0; qg < 4; ++qg) {
#pragma unroll
                for (int kg = 0; kg < 2; ++kg) {
                    f32x4 s = {0.f, 0.f, 0.f, 0.f};
                    s = MFMA16(qa[qg][0], kb[kg][0], s);
                    s = MFMA16(qa[qg][1], kb[kg][1], s);
                    float p0 = exp2f(s[0]);
                    float p1 = exp2f(s[1]);
                    float p2 = exp2f(s[2]);
                    float p3 = exp2f(s[3]);
                    if (diag) {
                        int qoff = qg * 16 + 4 * lg;
                        int kk = hf * 32 + kg * 16 + l15;
                        if (qoff + 0 <= kk) p0 = 0.f;
                        if (qoff + 1 <= kk) p1 = 0.f;
                        if (qoff + 2 <= kk) p2 = 0.f;
                        if (qoff + 3 <= kk) p3 = 0.f;
                    }
                    unsigned u0 = pack2bf(p0, p1);
                    unsigned u1 = pack2bf(p2, p3);
                    int row = kg * 16 + l15;
                    int col = (qg * 16 + 4 * lg) ^ ((row & 7) << 3);
                    uint2 val;
                    val.x = u0;
                    val.y = u1;
                    *(uint2*)&plw[row * 64 + col] = val;
                }
            }
        }
        // ---- batched V loads: all 8 issued back-to-back, in flight together,
        //      overlapping the P ds_write -> ds_read LDS latency ----
        bf16x8 vb[2][4];
#pragma unroll
        for (int qhh = 0; qhh < 2; ++qhh) {
            int chunk = (qhh << 2) | lg;
#pragma unroll
            for (int ds_ = 0; ds_ < 4; ++ds_) {
                const short* vp2 = vbase + (size_t)(ds_ * 16 + l15) * SS + qt * 64 + chunk * 8;
                vb[qhh][ds_] = *(const bf16x8*)vp2;
            }
        }
        // ---- PV phase ----
        __builtin_amdgcn_s_setprio(1);
#pragma unroll
        for (int qhh = 0; qhh < 2; ++qhh) {
            int chunk = (qhh << 2) | lg;
            int cc = (chunk ^ (l15 & 7)) << 3;
            bf16x8 pa0 = *(const bf16x8*)&plw[l15 * 64 + cc];
            bf16x8 pa1 = *(const bf16x8*)&plw[(16 + l15) * 64 + cc];
#pragma unroll
            for (int ds_ = 0; ds_ < 4; ++ds_) {
                acc[0][ds_] = MFMA16(pa0, vb[qhh][ds_], acc[0][ds_]);
                acc[1][ds_] = MFMA16(pa1, vb[qhh][ds_], acc[1][ds_]);
            }
        }
        __builtin_amdgcn_s_setprio(0);
    }

#pragma unroll
    for (int rg = 0; rg < 2; ++rg)
#pragma unroll
        for (int ds_ = 0; ds_ < 4; ++ds_) {
            int d = ds_ * 16 + l15;
#pragma unroll
            for (int r = 0; r < 4; ++r) {
                int k = row0 + rg * 16 + lg * 4 + r;
                attc[((size_t)b * SS + k) * 2048 + ph * 512 + h * 64 + d] =
                    f2bf(acc[rg][ds_][r]);
            }
        }
}

// ---------- Kernel 4: out = attc(4096x2048) @ [Wo x4](2048x64) via MFMA -------
__global__ __launch_bounds__(256) void outproj_kernel(
    const short* __restrict__ attc, const short* __restrict__ WoT,
    float* __restrict__ out) {
    int blk = blockIdx.x;
    int t = threadIdx.x, w = t >> 6, lane = t & 63;
    int l15 = lane & 15, lg = lane >> 4;
    int srow = blk * 16 + l15;
    const short* arow = attc + (size_t)srow * 2048 + lg * 8;

    f32x4 acc[4];
#pragma unroll
    for (int i = 0; i < 4; ++i) acc[i] = (f32x4){0.f, 0.f, 0.f, 0.f};

#pragma unroll
    for (int i = 0; i < 16; ++i) {
        int kc = w * 16 + i;
        bf16x8 af = *(const bf16x8*)(arow + kc * 32);
#pragma unroll
        for (int ds_ = 0; ds_ < 4; ++ds_) {
            bf16x8 bf_ = *(const bf16x8*)&WoT[(size_t)(ds_ * 16 + l15) * 2048 + kc * 32 + lg * 8];
            acc[ds_] = MFMA16(af, bf_, acc[ds_]);
        }
    }
    __shared__ float red[4][16 * 64];
#pragma unroll
    for (int ds_ = 0; ds_ < 4; ++ds_)
#pragma unroll
        for (int r = 0; r < 4; ++r)
            red[w][(lg * 4 + r) * 64 + ds_ * 16 + l15] = acc[ds_][r];
    __syncthreads();
    {
        int idx4 = t * 4;
        int row = idx4 >> 6, col = idx4 & 63;
        float4 s0 = *(const float4*)&red[0][row * 64 + col];
        float4 s1 = *(const float4*)&red[1][row * 64 + col];
        float4 s2 = *(const float4*)&red[2][row * 64 + col];
        float4 s3 = *(const float4*)&red[3][row * 64 + col];
        float4 sum;
        sum.x = s0.x + s1.x + s2.x + s3.x;
        sum.y = s0.y + s1.y + s2.y + s3.y;
        sum.z = s0.z + s1.z + s2.z + s3.z;
        sum.w = s0.w + s1.w + s2.w + s3.w;
        *(float4*)&out[(size_t)(blk * 16 + row) * 64 + col] = sum;
    }
}

extern "C" void kernel_launch(void* const* d_in, const int* in_sizes, int n_in,
                              void* d_out, int out_size, void* d_ws, size_t ws_size,
                              hipStream_t stream) {
    const float* q  = (const float*)d_in[0];
    const float* k  = (const float*)d_in[1];
    const float* v  = (const float*)d_in[2];
    const float* Wq = (const float*)d_in[3];
    const float* Wk = (const float*)d_in[4];
    const float* Wv = (const float*)d_in[5];
    const float* Wo = (const float*)d_in[6];
    float* out = (float*)d_out;

    const size_t PROJ = (size_t)NBH * SS * D;

    short* qh  = (short*)d_ws;
    short* kh  = qh + PROJ;
    short* vhT = kh + PROJ;
    short* WqT = vhT + PROJ;
    short* WkT = WqT + 32768;
    short* WvT = WkT + 32768;
    short* WoT = WvT + 32768;                         // 64*2048
    float* lpart = (float*)(WoT + 131072);            // KPAR*NBH*SS floats
    short* attc  = (short*)(lpart + (size_t)KPAR * NBH * SS);  // BB*SS*2048 bf16

    wtrans_kernel<<<40, 256, 0, stream>>>(Wq, Wk, Wv, Wo, WqT, WkT, WvT, WoT);

    proj_mfma_kernel<<<3 * NBH * 32, 256, 0, stream>>>(q, k, v, WqT, WkT, WvT,
                                                       qh, kh, vhT);

    colstats_kernel<<<NBH * 64, 256, 0, stream>>>(qh, kh, lpart);

    merge_scale_kernel<<<NBH * 16, 256, 0, stream>>>(lpart, vhT);

    pv_kernel<<<NBH * 64, 256, 0, stream>>>(qh, kh, vhT, attc);

    outproj_kernel<<<256, 256, 0, stream>>>(attc, WoT, out);
}